// Round 1
// baseline (3199.369 us; speedup 1.0000x reference)
//
#include <hip/hip_runtime.h>

// Decoder: T=32-step attention LSTM, BATCH=LATENT=HIDDEN=1024.
// Strategy:
//   setup (once per launch, inside graph):
//     - transpose weights f32[K][N] -> bf16[N][K] (B^T form for MFMA GEMM)
//       Wzh_t[4096][2048] = [Wk[1024:2048]; Wr]^T, Wk1_t[4096][1024], W1t, W2t
//     - latent -> bf16, A2=[h0|c0] bf16, A1[:,1024:]=h0 bf16, c_st=c0 f32
//     - z_lat = latent@Wk_top + b          (f32 [1024][4096])
//     - s_lat = latent@W1 + (b1+b2)        (f32 [1024][1024])
//     - spre = s_lat + A2@W2t ; attention -> ctx -> A1[:,0:1024]
//   per step t:
//     - z = z_lat + A1@Wzh_t               (MFMA GEMM, acc-init from z_lat)
//     - LSTM elementwise + fused out-projection (out[b*32+t])
//     - (t<31) spre = s_lat + A2@W2t ; tanh-softmax-context -> A1 ctx
// GEMM: m97 structure, 128x128 tile, BK=64, 4 waves, 16x16x32 bf16 MFMA,
// global_load_lds width=16 staging. ws usage ~88 MB.

#define T_ 32

typedef __attribute__((ext_vector_type(8))) short short8;
typedef __attribute__((ext_vector_type(4))) float f32x4;

__device__ __forceinline__ unsigned short bf16u(float x) {
  unsigned int u = __float_as_uint(x);
  u += 0x7FFFu + ((u >> 16) & 1u);
  return (unsigned short)(u >> 16);
}

__device__ __forceinline__ ushort4 pack4(float a, float b, float c, float d) {
  ushort4 v; v.x = bf16u(a); v.y = bf16u(b); v.z = bf16u(c); v.w = bf16u(d); return v;
}

__device__ __forceinline__ float sigmoidf_(float x) { return 1.f / (1.f + __expf(-x)); }
__device__ __forceinline__ float tanhf_(float x) { return 1.f - 2.f / (__expf(2.f * x) + 1.f); }

// ---------- transpose f32 [srcK][srcN] -> bf16 dst[n][dstStride] at col offset ----------
__global__ void k_transpose(const float* __restrict__ src, int srcN,
                            unsigned short* __restrict__ dst, int dstStride, int dstColOff) {
  __shared__ float tile[32][33];
  int n0 = blockIdx.x * 32, k0 = blockIdx.y * 32;
  int tx = threadIdx.x, ty = threadIdx.y;
#pragma unroll
  for (int i = 0; i < 4; ++i)
    tile[ty + i * 8][tx] = src[(size_t)(k0 + ty + i * 8) * srcN + n0 + tx];
  __syncthreads();
#pragma unroll
  for (int i = 0; i < 4; ++i)
    dst[(size_t)(n0 + ty + i * 8) * dstStride + dstColOff + k0 + tx] = bf16u(tile[tx][ty + i * 8]);
}

// ---------- one-time init: bf16 copies + c state ----------
__global__ __launch_bounds__(256) void k_init(const float* __restrict__ h0,
                                              const float* __restrict__ c0,
                                              const float* __restrict__ latent,
                                              unsigned short* __restrict__ A1,
                                              unsigned short* __restrict__ A2,
                                              unsigned short* __restrict__ latbf,
                                              float* __restrict__ c_st) {
  int r = blockIdx.x; int j = threadIdx.x * 4;
  const float4 hv = *(const float4*)&h0[(size_t)r * 1024 + j];
  const float4 cv = *(const float4*)&c0[(size_t)r * 1024 + j];
  const float4 lv = *(const float4*)&latent[(size_t)r * 1024 + j];
  *(ushort4*)&A2[(size_t)r * 2048 + j]        = pack4(hv.x, hv.y, hv.z, hv.w);
  *(ushort4*)&A2[(size_t)r * 2048 + 1024 + j] = pack4(cv.x, cv.y, cv.z, cv.w);
  *(ushort4*)&A1[(size_t)r * 2048 + 1024 + j] = pack4(hv.x, hv.y, hv.z, hv.w);
  *(ushort4*)&latbf[(size_t)r * 1024 + j]     = pack4(lv.x, lv.y, lv.z, lv.w);
  *(float4*)&c_st[(size_t)r * 1024 + j] = cv;
}

__global__ void k_bias(const float* __restrict__ b1, const float* __restrict__ b2,
                       float* __restrict__ bias_s) {
  int i = blockIdx.x * 256 + threadIdx.x;
  bias_s[i] = b1[i] + b2[i];
}

// ---------- MFMA GEMM: C[M][N] = A_bf16[M][lda] @ Bt_bf16[N][ldb]^T + init ----------
// init_full==0: initp is bias[N]; init_full==1: initp is f32 [M][N] (ld=N)
__global__ __launch_bounds__(256) void k_gemm(const unsigned short* __restrict__ A, int lda,
                                              const unsigned short* __restrict__ Bt, int ldb,
                                              int K,
                                              const float* __restrict__ initp, int init_full,
                                              float* __restrict__ C, int N) {
  __shared__ unsigned short Al[128 * 64];
  __shared__ unsigned short Bl[128 * 64];
  const int tid = threadIdx.x;
  const int w = tid >> 6, l = tid & 63;
  const int row0 = blockIdx.y * 128, col0 = blockIdx.x * 128;
  const int wr = (w >> 1) * 64, wc = (w & 1) * 64;
  const int lr = l & 15, lkb = (l >> 4) * 8;
  const int srow = (l >> 3);        // 0..7 within chunk
  const int scol = (l & 7) * 8;     // k element within row

  f32x4 acc[4][4] = {};

  for (int k0 = 0; k0 < K; k0 += 64) {
#pragma unroll
    for (int it = 0; it < 4; ++it) {
      int chunk = w * 4 + it;           // wave-uniform
      int r = chunk * 8 + srow;
      const unsigned short* ga = A + (size_t)(row0 + r) * lda + k0 + scol;
      const unsigned short* gb = Bt + (size_t)(col0 + r) * ldb + k0 + scol;
      __builtin_amdgcn_global_load_lds(
          (const __attribute__((address_space(1))) unsigned int*)ga,
          (__attribute__((address_space(3))) unsigned int*)((char*)Al + chunk * 1024), 16, 0, 0);
      __builtin_amdgcn_global_load_lds(
          (const __attribute__((address_space(1))) unsigned int*)gb,
          (__attribute__((address_space(3))) unsigned int*)((char*)Bl + chunk * 1024), 16, 0, 0);
    }
    __syncthreads();   // compiler emits vmcnt(0) drain before barrier
#pragma unroll
    for (int kk = 0; kk < 2; ++kk) {
      short8 a[4], b[4];
#pragma unroll
      for (int m = 0; m < 4; ++m) a[m] = *(const short8*)&Al[(wr + m * 16 + lr) * 64 + kk * 32 + lkb];
#pragma unroll
      for (int n = 0; n < 4; ++n) b[n] = *(const short8*)&Bl[(wc + n * 16 + lr) * 64 + kk * 32 + lkb];
#pragma unroll
      for (int m = 0; m < 4; ++m)
#pragma unroll
        for (int n = 0; n < 4; ++n)
          acc[m][n] = __builtin_amdgcn_mfma_f32_16x16x32_bf16(a[m], b[n], acc[m][n], 0, 0, 0);
    }
    __syncthreads();
  }

  const int rbase = (l >> 4) * 4;
#pragma unroll
  for (int m = 0; m < 4; ++m) {
#pragma unroll
    for (int rg = 0; rg < 4; ++rg) {
      int row = row0 + wr + m * 16 + rbase + rg;
      const float* ini = init_full ? (initp + (size_t)row * N) : initp;
#pragma unroll
      for (int n = 0; n < 4; ++n) {
        int col = col0 + wc + n * 16 + lr;
        C[(size_t)row * N + col] = acc[m][n][rg] + ini[col];
      }
    }
  }
}

// ---------- LSTM elementwise + fused out-projection ----------
__global__ __launch_bounds__(256) void k_lstm(const float* __restrict__ z,
                                              float* __restrict__ c_st,
                                              unsigned short* __restrict__ A1,
                                              unsigned short* __restrict__ A2,
                                              const float* __restrict__ Wmu,
                                              const float* __restrict__ bmu,
                                              float* __restrict__ out, int t) {
  __shared__ float red[4];
  int r = blockIdx.x; int tid = threadIdx.x; int j = tid * 4;
  const float4 zi = *(const float4*)&z[(size_t)r * 4096 + j];
  const float4 zf = *(const float4*)&z[(size_t)r * 4096 + 1024 + j];
  const float4 zg = *(const float4*)&z[(size_t)r * 4096 + 2048 + j];
  const float4 zo = *(const float4*)&z[(size_t)r * 4096 + 3072 + j];
  const float4 cv = *(const float4*)&c_st[(size_t)r * 1024 + j];
  const float4 wm = *(const float4*)&Wmu[j];
  float iv[4] = {zi.x, zi.y, zi.z, zi.w}, fv[4] = {zf.x, zf.y, zf.z, zf.w};
  float gv[4] = {zg.x, zg.y, zg.z, zg.w}, ov[4] = {zo.x, zo.y, zo.z, zo.w};
  float cc[4] = {cv.x, cv.y, cv.z, cv.w}, wv[4] = {wm.x, wm.y, wm.z, wm.w};
  float cn[4], hn[4];
  float part = 0.f;
#pragma unroll
  for (int q = 0; q < 4; ++q) {
    float c2 = sigmoidf_(fv[q]) * cc[q] + sigmoidf_(iv[q]) * tanhf_(gv[q]);
    float h2 = sigmoidf_(ov[q]) * tanhf_(c2);
    cn[q] = c2; hn[q] = h2; part += h2 * wv[q];
  }
  *(float4*)&c_st[(size_t)r * 1024 + j] = make_float4(cn[0], cn[1], cn[2], cn[3]);
  *(ushort4*)&A2[(size_t)r * 2048 + j]        = pack4(hn[0], hn[1], hn[2], hn[3]);
  *(ushort4*)&A2[(size_t)r * 2048 + 1024 + j] = pack4(cn[0], cn[1], cn[2], cn[3]);
  *(ushort4*)&A1[(size_t)r * 2048 + 1024 + j] = pack4(hn[0], hn[1], hn[2], hn[3]);
#pragma unroll
  for (int off = 32; off > 0; off >>= 1) part += __shfl_down(part, off, 64);
  if ((tid & 63) == 0) red[tid >> 6] = part;
  __syncthreads();
  if (tid == 0) out[(size_t)r * T_ + t] = red[0] + red[1] + red[2] + red[3] + bmu[0];
}

// ---------- attention: tanh -> softmax(features) -> ctx = beta*latent -> A1[:,0:1024] bf16 ----------
__global__ __launch_bounds__(256) void k_attn(const float* __restrict__ spre,
                                              const float* __restrict__ latent,
                                              unsigned short* __restrict__ A1) {
  __shared__ float red[4];
  int r = blockIdx.x; int tid = threadIdx.x; int j = tid * 4;
  const float4 sp = *(const float4*)&spre[(size_t)r * 1024 + j];
  float s[4] = {tanhf_(sp.x), tanhf_(sp.y), tanhf_(sp.z), tanhf_(sp.w)};
  float mx = fmaxf(fmaxf(s[0], s[1]), fmaxf(s[2], s[3]));
#pragma unroll
  for (int off = 32; off > 0; off >>= 1) mx = fmaxf(mx, __shfl_xor(mx, off, 64));
  if ((tid & 63) == 0) red[tid >> 6] = mx;
  __syncthreads();
  mx = fmaxf(fmaxf(red[0], red[1]), fmaxf(red[2], red[3]));
  __syncthreads();
  float e[4], ps = 0.f;
#pragma unroll
  for (int q = 0; q < 4; ++q) { e[q] = __expf(s[q] - mx); ps += e[q]; }
#pragma unroll
  for (int off = 32; off > 0; off >>= 1) ps += __shfl_xor(ps, off, 64);
  if ((tid & 63) == 0) red[tid >> 6] = ps;
  __syncthreads();
  float inv = 1.f / (red[0] + red[1] + red[2] + red[3]);
  const float4 lv = *(const float4*)&latent[(size_t)r * 1024 + j];
  float lvv[4] = {lv.x, lv.y, lv.z, lv.w};
  *(ushort4*)&A1[(size_t)r * 2048 + j] =
      pack4(e[0] * inv * lvv[0], e[1] * inv * lvv[1], e[2] * inv * lvv[2], e[3] * inv * lvv[3]);
}

extern "C" void kernel_launch(void* const* d_in, const int* in_sizes, int n_in,
                              void* d_out, int out_size, void* d_ws, size_t ws_size,
                              hipStream_t stream) {
  const float* latent = (const float*)d_in[0];
  const float* h0  = (const float*)d_in[1];
  const float* c0  = (const float*)d_in[2];
  const float* Wk  = (const float*)d_in[3];
  const float* Wr  = (const float*)d_in[4];
  const float* b   = (const float*)d_in[5];
  const float* W1  = (const float*)d_in[6];
  const float* b1  = (const float*)d_in[7];
  const float* W2  = (const float*)d_in[8];
  const float* b2  = (const float*)d_in[9];
  const float* Wmu = (const float*)d_in[10];
  const float* bmu = (const float*)d_in[11];
  float* out = (float*)d_out;

  char* p = (char*)d_ws;
  auto alloc = [&](size_t bytes) { void* r = (void*)p; p += (bytes + 255) & ~(size_t)255; return r; };
  unsigned short* Wzh_t = (unsigned short*)alloc((size_t)4096 * 2048 * 2);  // [n][k] k<1024:Wk_bot, else Wr
  unsigned short* Wk1_t = (unsigned short*)alloc((size_t)4096 * 1024 * 2);  // Wk_top^T
  unsigned short* W1t   = (unsigned short*)alloc((size_t)1024 * 1024 * 2);
  unsigned short* W2t   = (unsigned short*)alloc((size_t)1024 * 2048 * 2);
  unsigned short* latbf = (unsigned short*)alloc((size_t)1024 * 1024 * 2);
  unsigned short* A1    = (unsigned short*)alloc((size_t)1024 * 2048 * 2);  // [ctx | h] bf16
  unsigned short* A2    = (unsigned short*)alloc((size_t)1024 * 2048 * 2);  // [h | c] bf16
  float* z_lat  = (float*)alloc((size_t)1024 * 4096 * 4);
  float* s_lat  = (float*)alloc((size_t)1024 * 1024 * 4);
  float* z      = (float*)alloc((size_t)1024 * 4096 * 4);
  float* spre   = (float*)alloc((size_t)1024 * 1024 * 4);
  float* c_st   = (float*)alloc((size_t)1024 * 1024 * 4);
  float* bias_s = (float*)alloc((size_t)1024 * 4);

  dim3 tb(32, 8);
  // weight transposes (f32 [K][N] -> bf16 [N][K])
  k_transpose<<<dim3(128, 32), tb, 0, stream>>>(Wk, 4096, Wk1_t, 1024, 0);
  k_transpose<<<dim3(128, 32), tb, 0, stream>>>(Wk + (size_t)1024 * 4096, 4096, Wzh_t, 2048, 0);
  k_transpose<<<dim3(128, 32), tb, 0, stream>>>(Wr, 4096, Wzh_t, 2048, 1024);
  k_transpose<<<dim3(32, 64), tb, 0, stream>>>(W2, 1024, W2t, 2048, 0);
  k_transpose<<<dim3(32, 32), tb, 0, stream>>>(W1, 1024, W1t, 1024, 0);

  k_init<<<1024, 256, 0, stream>>>(h0, c0, latent, A1, A2, latbf, c_st);
  k_bias<<<4, 256, 0, stream>>>(b1, b2, bias_s);

  // z_lat = latent@Wk_top + b ; s_lat = latent@W1 + (b1+b2)
  k_gemm<<<dim3(32, 8), 256, 0, stream>>>(latbf, 1024, Wk1_t, 1024, 1024, b, 0, z_lat, 4096);
  k_gemm<<<dim3(8, 8), 256, 0, stream>>>(latbf, 1024, W1t, 1024, 1024, bias_s, 0, s_lat, 1024);

  // initial attention from (h0, c0)
  k_gemm<<<dim3(8, 8), 256, 0, stream>>>(A2, 2048, W2t, 2048, 2048, s_lat, 1, spre, 1024);
  k_attn<<<1024, 256, 0, stream>>>(spre, latent, A1);

  for (int t = 0; t < T_; ++t) {
    k_gemm<<<dim3(32, 8), 256, 0, stream>>>(A1, 2048, Wzh_t, 2048, 2048, z_lat, 1, z, 4096);
    k_lstm<<<1024, 256, 0, stream>>>(z, c_st, A1, A2, Wmu, bmu, out, t);
    if (t < T_ - 1) {
      k_gemm<<<dim3(8, 8), 256, 0, stream>>>(A2, 2048, W2t, 2048, 2048, s_lat, 1, spre, 1024);
      k_attn<<<1024, 256, 0, stream>>>(spre, latent, A1);
    }
  }
}

// Round 2
// 2720.586 us; speedup vs baseline: 1.1760x; 1.1760x over previous
//
#include <hip/hip_runtime.h>

// Decoder: T=32-step attention LSTM, BATCH=LATENT=HIDDEN=1024.
// R2: split-K GEMMs (512 WGs = 2 blocks/CU) + 2-phase double-buffered LDS.
//   GEMM1 (z):    grid (32,8,2), Kchunk=1024 -> z_part[2]
//   GEMM2 (spre): grid (8,8,8),  Kchunk=256  -> spre_part[8]
//   k_lstm sums z partials; k_attn sums spre partials.

#define T_ 32

typedef __attribute__((ext_vector_type(8))) short short8;
typedef __attribute__((ext_vector_type(4))) float f32x4;

__device__ __forceinline__ unsigned short bf16u(float x) {
  unsigned int u = __float_as_uint(x);
  u += 0x7FFFu + ((u >> 16) & 1u);
  return (unsigned short)(u >> 16);
}

__device__ __forceinline__ ushort4 pack4(float a, float b, float c, float d) {
  ushort4 v; v.x = bf16u(a); v.y = bf16u(b); v.z = bf16u(c); v.w = bf16u(d); return v;
}

__device__ __forceinline__ float sigmoidf_(float x) { return 1.f / (1.f + __expf(-x)); }
__device__ __forceinline__ float tanhf_(float x) { return 1.f - 2.f / (__expf(2.f * x) + 1.f); }

// ---------- transpose f32 [srcK][srcN] -> bf16 dst[n][dstStride] at col offset ----------
__global__ void k_transpose(const float* __restrict__ src, int srcN,
                            unsigned short* __restrict__ dst, int dstStride, int dstColOff) {
  __shared__ float tile[32][33];
  int n0 = blockIdx.x * 32, k0 = blockIdx.y * 32;
  int tx = threadIdx.x, ty = threadIdx.y;
#pragma unroll
  for (int i = 0; i < 4; ++i)
    tile[ty + i * 8][tx] = src[(size_t)(k0 + ty + i * 8) * srcN + n0 + tx];
  __syncthreads();
#pragma unroll
  for (int i = 0; i < 4; ++i)
    dst[(size_t)(n0 + ty + i * 8) * dstStride + dstColOff + k0 + tx] = bf16u(tile[tx][ty + i * 8]);
}

// ---------- one-time init: bf16 copies + c state ----------
__global__ __launch_bounds__(256) void k_init(const float* __restrict__ h0,
                                              const float* __restrict__ c0,
                                              const float* __restrict__ latent,
                                              unsigned short* __restrict__ A1,
                                              unsigned short* __restrict__ A2,
                                              unsigned short* __restrict__ latbf,
                                              float* __restrict__ c_st) {
  int r = blockIdx.x; int j = threadIdx.x * 4;
  const float4 hv = *(const float4*)&h0[(size_t)r * 1024 + j];
  const float4 cv = *(const float4*)&c0[(size_t)r * 1024 + j];
  const float4 lv = *(const float4*)&latent[(size_t)r * 1024 + j];
  *(ushort4*)&A2[(size_t)r * 2048 + j]        = pack4(hv.x, hv.y, hv.z, hv.w);
  *(ushort4*)&A2[(size_t)r * 2048 + 1024 + j] = pack4(cv.x, cv.y, cv.z, cv.w);
  *(ushort4*)&A1[(size_t)r * 2048 + 1024 + j] = pack4(hv.x, hv.y, hv.z, hv.w);
  *(ushort4*)&latbf[(size_t)r * 1024 + j]     = pack4(lv.x, lv.y, lv.z, lv.w);
  *(float4*)&c_st[(size_t)r * 1024 + j] = cv;
}

__global__ void k_bias(const float* __restrict__ b1, const float* __restrict__ b2,
                       float* __restrict__ bias_s) {
  int i = blockIdx.x * 256 + threadIdx.x;
  bias_s[i] = b1[i] + b2[i];
}

// ---------- MFMA GEMM (split-K, 2-phase dbuf) ----------
// C_part[z][M][N] ; chunk z covers K rows [z*Kchunk, (z+1)*Kchunk).
// chunk 0 adds init (bias[N] if !init_full, else f32 [M][N]); others raw.
__global__ __launch_bounds__(256) void k_gemm(const unsigned short* __restrict__ A, int lda,
                                              const unsigned short* __restrict__ Bt, int ldb,
                                              int Kchunk,
                                              const float* __restrict__ initp, int init_full,
                                              float* __restrict__ C, int N) {
  __shared__ unsigned short Al[2][128 * 64];
  __shared__ unsigned short Bl[2][128 * 64];
  const int tid = threadIdx.x;
  const int w = tid >> 6, l = tid & 63;
  const int row0 = blockIdx.y * 128, col0 = blockIdx.x * 128;
  const int wr = (w >> 1) * 64, wc = (w & 1) * 64;
  const int lr = l & 15, lkb = (l >> 4) * 8;
  const int srow = (l >> 3);        // 0..7 within chunk
  const int scol = (l & 7) * 8;     // k element within row
  const int kbeg = blockIdx.z * Kchunk;
  const int nsteps = Kchunk >> 6;

  f32x4 acc[4][4] = {};

  auto stage = [&](int buf, int k0) {
#pragma unroll
    for (int it = 0; it < 4; ++it) {
      int chunk = w * 4 + it;           // wave-uniform
      int r = chunk * 8 + srow;
      const unsigned short* ga = A + (size_t)(row0 + r) * lda + k0 + scol;
      const unsigned short* gb = Bt + (size_t)(col0 + r) * ldb + k0 + scol;
      __builtin_amdgcn_global_load_lds(
          (const __attribute__((address_space(1))) unsigned int*)ga,
          (__attribute__((address_space(3))) unsigned int*)((char*)&Al[buf][0] + chunk * 1024), 16, 0, 0);
      __builtin_amdgcn_global_load_lds(
          (const __attribute__((address_space(1))) unsigned int*)gb,
          (__attribute__((address_space(3))) unsigned int*)((char*)&Bl[buf][0] + chunk * 1024), 16, 0, 0);
    }
  };

  stage(0, kbeg);
  __syncthreads();
  int cur = 0;
  for (int s = 0; s < nsteps; ++s) {
    if (s + 1 < nsteps) stage(cur ^ 1, kbeg + (s + 1) * 64);  // prefetch next tile
#pragma unroll
    for (int kk = 0; kk < 2; ++kk) {
      short8 a[4], b[4];
#pragma unroll
      for (int m = 0; m < 4; ++m) a[m] = *(const short8*)&Al[cur][(wr + m * 16 + lr) * 64 + kk * 32 + lkb];
#pragma unroll
      for (int n = 0; n < 4; ++n) b[n] = *(const short8*)&Bl[cur][(wc + n * 16 + lr) * 64 + kk * 32 + lkb];
#pragma unroll
      for (int m = 0; m < 4; ++m)
#pragma unroll
        for (int n = 0; n < 4; ++n)
          acc[m][n] = __builtin_amdgcn_mfma_f32_16x16x32_bf16(a[m], b[n], acc[m][n], 0, 0, 0);
    }
    __syncthreads();   // drains prefetch (vmcnt0) + all waves done with cur
    cur ^= 1;
  }

  float* Cp = C + (size_t)blockIdx.z * (size_t)(gridDim.y * 128) * N;
  const int rbase = (l >> 4) * 4;
#pragma unroll
  for (int m = 0; m < 4; ++m) {
#pragma unroll
    for (int rg = 0; rg < 4; ++rg) {
      int row = row0 + wr + m * 16 + rbase + rg;
      const float* ini = init_full ? (initp + (size_t)row * N) : initp;
#pragma unroll
      for (int n = 0; n < 4; ++n) {
        int col = col0 + wc + n * 16 + lr;
        float v = acc[m][n][rg];
        if (blockIdx.z == 0) v += ini[col];
        Cp[(size_t)row * N + col] = v;
      }
    }
  }
}

// ---------- LSTM elementwise (sums 2 z-partials) + fused out-projection ----------
__global__ __launch_bounds__(256) void k_lstm(const float* __restrict__ z,
                                              float* __restrict__ c_st,
                                              unsigned short* __restrict__ A1,
                                              unsigned short* __restrict__ A2,
                                              const float* __restrict__ Wmu,
                                              const float* __restrict__ bmu,
                                              float* __restrict__ out, int t) {
  __shared__ float red[4];
  const size_t Z1 = (size_t)1024 * 4096;
  int r = blockIdx.x; int tid = threadIdx.x; int j = tid * 4;
  const float4 zi0 = *(const float4*)&z[(size_t)r * 4096 + j];
  const float4 zf0 = *(const float4*)&z[(size_t)r * 4096 + 1024 + j];
  const float4 zg0 = *(const float4*)&z[(size_t)r * 4096 + 2048 + j];
  const float4 zo0 = *(const float4*)&z[(size_t)r * 4096 + 3072 + j];
  const float4 zi1 = *(const float4*)&z[Z1 + (size_t)r * 4096 + j];
  const float4 zf1 = *(const float4*)&z[Z1 + (size_t)r * 4096 + 1024 + j];
  const float4 zg1 = *(const float4*)&z[Z1 + (size_t)r * 4096 + 2048 + j];
  const float4 zo1 = *(const float4*)&z[Z1 + (size_t)r * 4096 + 3072 + j];
  const float4 cv = *(const float4*)&c_st[(size_t)r * 1024 + j];
  const float4 wm = *(const float4*)&Wmu[j];
  float iv[4] = {zi0.x + zi1.x, zi0.y + zi1.y, zi0.z + zi1.z, zi0.w + zi1.w};
  float fv[4] = {zf0.x + zf1.x, zf0.y + zf1.y, zf0.z + zf1.z, zf0.w + zf1.w};
  float gv[4] = {zg0.x + zg1.x, zg0.y + zg1.y, zg0.z + zg1.z, zg0.w + zg1.w};
  float ov[4] = {zo0.x + zo1.x, zo0.y + zo1.y, zo0.z + zo1.z, zo0.w + zo1.w};
  float cc[4] = {cv.x, cv.y, cv.z, cv.w}, wv[4] = {wm.x, wm.y, wm.z, wm.w};
  float cn[4], hn[4];
  float part = 0.f;
#pragma unroll
  for (int q = 0; q < 4; ++q) {
    float c2 = sigmoidf_(fv[q]) * cc[q] + sigmoidf_(iv[q]) * tanhf_(gv[q]);
    float h2 = sigmoidf_(ov[q]) * tanhf_(c2);
    cn[q] = c2; hn[q] = h2; part += h2 * wv[q];
  }
  *(float4*)&c_st[(size_t)r * 1024 + j] = make_float4(cn[0], cn[1], cn[2], cn[3]);
  *(ushort4*)&A2[(size_t)r * 2048 + j]        = pack4(hn[0], hn[1], hn[2], hn[3]);
  *(ushort4*)&A2[(size_t)r * 2048 + 1024 + j] = pack4(cn[0], cn[1], cn[2], cn[3]);
  *(ushort4*)&A1[(size_t)r * 2048 + 1024 + j] = pack4(hn[0], hn[1], hn[2], hn[3]);
#pragma unroll
  for (int off = 32; off > 0; off >>= 1) part += __shfl_down(part, off, 64);
  if ((tid & 63) == 0) red[tid >> 6] = part;
  __syncthreads();
  if (tid == 0) out[(size_t)r * T_ + t] = red[0] + red[1] + red[2] + red[3] + bmu[0];
}

// ---------- attention: sum 8 spre partials -> tanh -> softmax -> ctx -> A1[:,0:1024] ----------
__global__ __launch_bounds__(256) void k_attn(const float* __restrict__ spre,
                                              const float* __restrict__ latent,
                                              unsigned short* __restrict__ A1) {
  __shared__ float red[4];
  const size_t P = (size_t)1024 * 1024;
  int r = blockIdx.x; int tid = threadIdx.x; int j = tid * 4;
  float4 sp = *(const float4*)&spre[(size_t)r * 1024 + j];
#pragma unroll
  for (int sidx = 1; sidx < 8; ++sidx) {
    const float4 q = *(const float4*)&spre[sidx * P + (size_t)r * 1024 + j];
    sp.x += q.x; sp.y += q.y; sp.z += q.z; sp.w += q.w;
  }
  float s[4] = {tanhf_(sp.x), tanhf_(sp.y), tanhf_(sp.z), tanhf_(sp.w)};
  float mx = fmaxf(fmaxf(s[0], s[1]), fmaxf(s[2], s[3]));
#pragma unroll
  for (int off = 32; off > 0; off >>= 1) mx = fmaxf(mx, __shfl_xor(mx, off, 64));
  if ((tid & 63) == 0) red[tid >> 6] = mx;
  __syncthreads();
  mx = fmaxf(fmaxf(red[0], red[1]), fmaxf(red[2], red[3]));
  __syncthreads();
  float e[4], ps = 0.f;
#pragma unroll
  for (int q = 0; q < 4; ++q) { e[q] = __expf(s[q] - mx); ps += e[q]; }
#pragma unroll
  for (int off = 32; off > 0; off >>= 1) ps += __shfl_xor(ps, off, 64);
  if ((tid & 63) == 0) red[tid >> 6] = ps;
  __syncthreads();
  float inv = 1.f / (red[0] + red[1] + red[2] + red[3]);
  const float4 lv = *(const float4*)&latent[(size_t)r * 1024 + j];
  float lvv[4] = {lv.x, lv.y, lv.z, lv.w};
  *(ushort4*)&A1[(size_t)r * 2048 + j] =
      pack4(e[0] * inv * lvv[0], e[1] * inv * lvv[1], e[2] * inv * lvv[2], e[3] * inv * lvv[3]);
}

extern "C" void kernel_launch(void* const* d_in, const int* in_sizes, int n_in,
                              void* d_out, int out_size, void* d_ws, size_t ws_size,
                              hipStream_t stream) {
  const float* latent = (const float*)d_in[0];
  const float* h0  = (const float*)d_in[1];
  const float* c0  = (const float*)d_in[2];
  const float* Wk  = (const float*)d_in[3];
  const float* Wr  = (const float*)d_in[4];
  const float* b   = (const float*)d_in[5];
  const float* W1  = (const float*)d_in[6];
  const float* b1  = (const float*)d_in[7];
  const float* W2  = (const float*)d_in[8];
  const float* b2  = (const float*)d_in[9];
  const float* Wmu = (const float*)d_in[10];
  const float* bmu = (const float*)d_in[11];
  float* out = (float*)d_out;

  char* p = (char*)d_ws;
  auto alloc = [&](size_t bytes) { void* r = (void*)p; p += (bytes + 255) & ~(size_t)255; return r; };
  unsigned short* Wzh_t = (unsigned short*)alloc((size_t)4096 * 2048 * 2);
  unsigned short* Wk1_t = (unsigned short*)alloc((size_t)4096 * 1024 * 2);
  unsigned short* W1t   = (unsigned short*)alloc((size_t)1024 * 1024 * 2);
  unsigned short* W2t   = (unsigned short*)alloc((size_t)1024 * 2048 * 2);
  unsigned short* latbf = (unsigned short*)alloc((size_t)1024 * 1024 * 2);
  unsigned short* A1    = (unsigned short*)alloc((size_t)1024 * 2048 * 2);  // [ctx | h] bf16
  unsigned short* A2    = (unsigned short*)alloc((size_t)1024 * 2048 * 2);  // [h | c] bf16
  float* z_lat  = (float*)alloc((size_t)1024 * 4096 * 4);
  float* s_lat  = (float*)alloc((size_t)1024 * 1024 * 4);
  float* z_part = (float*)alloc((size_t)2 * 1024 * 4096 * 4);
  float* spre_p = (float*)alloc((size_t)8 * 1024 * 1024 * 4);
  float* c_st   = (float*)alloc((size_t)1024 * 1024 * 4);
  float* bias_s = (float*)alloc((size_t)1024 * 4);

  dim3 tb(32, 8);
  k_transpose<<<dim3(128, 32), tb, 0, stream>>>(Wk, 4096, Wk1_t, 1024, 0);
  k_transpose<<<dim3(128, 32), tb, 0, stream>>>(Wk + (size_t)1024 * 4096, 4096, Wzh_t, 2048, 0);
  k_transpose<<<dim3(128, 32), tb, 0, stream>>>(Wr, 4096, Wzh_t, 2048, 1024);
  k_transpose<<<dim3(32, 64), tb, 0, stream>>>(W2, 1024, W2t, 2048, 0);
  k_transpose<<<dim3(32, 32), tb, 0, stream>>>(W1, 1024, W1t, 1024, 0);

  k_init<<<1024, 256, 0, stream>>>(h0, c0, latent, A1, A2, latbf, c_st);
  k_bias<<<4, 256, 0, stream>>>(b1, b2, bias_s);

  // setup GEMMs (once): z_lat = latent@Wk_top + b ; s_lat = latent@W1 + (b1+b2)
  k_gemm<<<dim3(32, 8, 1), 256, 0, stream>>>(latbf, 1024, Wk1_t, 1024, 1024, b, 0, z_lat, 4096);
  k_gemm<<<dim3(8, 8, 1), 256, 0, stream>>>(latbf, 1024, W1t, 1024, 1024, bias_s, 0, s_lat, 1024);

  // initial attention from (h0, c0)
  k_gemm<<<dim3(8, 8, 8), 256, 0, stream>>>(A2, 2048, W2t, 2048, 256, s_lat, 1, spre_p, 1024);
  k_attn<<<1024, 256, 0, stream>>>(spre_p, latent, A1);

  for (int t = 0; t < T_; ++t) {
    k_gemm<<<dim3(32, 8, 2), 256, 0, stream>>>(A1, 2048, Wzh_t, 2048, 1024, z_lat, 1, z_part, 4096);
    k_lstm<<<1024, 256, 0, stream>>>(z_part, c_st, A1, A2, Wmu, bmu, out, t);
    if (t < T_ - 1) {
      k_gemm<<<dim3(8, 8, 8), 256, 0, stream>>>(A2, 2048, W2t, 2048, 256, s_lat, 1, spre_p, 1024);
      k_attn<<<1024, 256, 0, stream>>>(spre_p, latent, A1);
    }
  }
}

// Round 3
// 1640.536 us; speedup vs baseline: 1.9502x; 1.6584x over previous
//
#include <hip/hip_runtime.h>

// Decoder: T=32-step attention LSTM, BATCH=LATENT=HIDDEN=1024.
// R3: T2 both-sides XOR swizzle in GEMM (kill 16-way LDS bank conflicts)
//     + bf16 split-K partials (z, spre); z_lat/s_lat stay f32, added in consumers.

#define T_ 32

typedef __attribute__((ext_vector_type(8))) short short8;
typedef __attribute__((ext_vector_type(4))) float f32x4;

__device__ __forceinline__ unsigned short bf16u(float x) {
  unsigned int u = __float_as_uint(x);
  u += 0x7FFFu + ((u >> 16) & 1u);
  return (unsigned short)(u >> 16);
}
__device__ __forceinline__ float b2f(unsigned short u) {
  return __uint_as_float(((unsigned int)u) << 16);
}
__device__ __forceinline__ ushort4 pack4(float a, float b, float c, float d) {
  ushort4 v; v.x = bf16u(a); v.y = bf16u(b); v.z = bf16u(c); v.w = bf16u(d); return v;
}
__device__ __forceinline__ float sigmoidf_(float x) { return 1.f / (1.f + __expf(-x)); }
__device__ __forceinline__ float tanhf_(float x) { return 1.f - 2.f / (__expf(2.f * x) + 1.f); }

// ---------- transpose f32 [srcK][srcN] -> bf16 dst[n][dstStride] at col offset ----------
__global__ void k_transpose(const float* __restrict__ src, int srcN,
                            unsigned short* __restrict__ dst, int dstStride, int dstColOff) {
  __shared__ float tile[32][33];
  int n0 = blockIdx.x * 32, k0 = blockIdx.y * 32;
  int tx = threadIdx.x, ty = threadIdx.y;
#pragma unroll
  for (int i = 0; i < 4; ++i)
    tile[ty + i * 8][tx] = src[(size_t)(k0 + ty + i * 8) * srcN + n0 + tx];
  __syncthreads();
#pragma unroll
  for (int i = 0; i < 4; ++i)
    dst[(size_t)(n0 + ty + i * 8) * dstStride + dstColOff + k0 + tx] = bf16u(tile[tx][ty + i * 8]);
}

// ---------- one-time init ----------
__global__ __launch_bounds__(256) void k_init(const float* __restrict__ h0,
                                              const float* __restrict__ c0,
                                              const float* __restrict__ latent,
                                              unsigned short* __restrict__ A1,
                                              unsigned short* __restrict__ A2,
                                              unsigned short* __restrict__ latbf,
                                              float* __restrict__ c_st) {
  int r = blockIdx.x; int j = threadIdx.x * 4;
  const float4 hv = *(const float4*)&h0[(size_t)r * 1024 + j];
  const float4 cv = *(const float4*)&c0[(size_t)r * 1024 + j];
  const float4 lv = *(const float4*)&latent[(size_t)r * 1024 + j];
  *(ushort4*)&A2[(size_t)r * 2048 + j]        = pack4(hv.x, hv.y, hv.z, hv.w);
  *(ushort4*)&A2[(size_t)r * 2048 + 1024 + j] = pack4(cv.x, cv.y, cv.z, cv.w);
  *(ushort4*)&A1[(size_t)r * 2048 + 1024 + j] = pack4(hv.x, hv.y, hv.z, hv.w);
  *(ushort4*)&latbf[(size_t)r * 1024 + j]     = pack4(lv.x, lv.y, lv.z, lv.w);
  *(float4*)&c_st[(size_t)r * 1024 + j] = cv;
}

__global__ void k_bias(const float* __restrict__ b1, const float* __restrict__ b2,
                       float* __restrict__ bias_s) {
  int i = blockIdx.x * 256 + threadIdx.x;
  bias_s[i] = b1[i] + b2[i];
}

// ---------- MFMA GEMM (split-K, 2-phase dbuf, T2 both-sides swizzle) ----------
// If Cf != nullptr: write f32 acc + bias[col] (setup GEMMs, gridDim.z==1).
// Else: write bf16 raw partial to Cb[z][M][N].
__global__ __launch_bounds__(256) void k_gemm(const unsigned short* __restrict__ A, int lda,
                                              const unsigned short* __restrict__ Bt, int ldb,
                                              int Kchunk,
                                              const float* __restrict__ bias,
                                              float* __restrict__ Cf,
                                              unsigned short* __restrict__ Cb, int N) {
  __shared__ unsigned short Al[2][128 * 64];
  __shared__ unsigned short Bl[2][128 * 64];
  const int tid = threadIdx.x;
  const int w = tid >> 6, l = tid & 63;
  const int row0 = blockIdx.y * 128, col0 = blockIdx.x * 128;
  const int wr = (w >> 1) * 64, wc = (w & 1) * 64;
  const int lr = l & 15, lkb = (l >> 4) * 8;
  const int srow = (l >> 3);                       // 0..7 within chunk
  const int scol_src = ((l & 7) ^ srow) * 8;       // swizzled global column (elements)
  const int kbeg = blockIdx.z * Kchunk;
  const int nsteps = Kchunk >> 6;

  f32x4 acc[4][4] = {};

  auto stage = [&](int buf, int k0) {
#pragma unroll
    for (int it = 0; it < 4; ++it) {
      int chunk = w * 4 + it;           // wave-uniform
      int r = chunk * 8 + srow;
      const unsigned short* ga = A + (size_t)(row0 + r) * lda + k0 + scol_src;
      const unsigned short* gb = Bt + (size_t)(col0 + r) * ldb + k0 + scol_src;
      __builtin_amdgcn_global_load_lds(
          (const __attribute__((address_space(1))) unsigned int*)ga,
          (__attribute__((address_space(3))) unsigned int*)((char*)&Al[buf][0] + chunk * 1024), 16, 0, 0);
      __builtin_amdgcn_global_load_lds(
          (const __attribute__((address_space(1))) unsigned int*)gb,
          (__attribute__((address_space(3))) unsigned int*)((char*)&Bl[buf][0] + chunk * 1024), 16, 0, 0);
    }
  };

  stage(0, kbeg);
  __syncthreads();
  int cur = 0;
  for (int s = 0; s < nsteps; ++s) {
    if (s + 1 < nsteps) stage(cur ^ 1, kbeg + (s + 1) * 64);  // prefetch next tile
#pragma unroll
    for (int kk = 0; kk < 2; ++kk) {
      const int c2 = kk * 64 + (l >> 4) * 16;     // byte col within 128B row
      short8 a[4], b[4];
#pragma unroll
      for (int m = 0; m < 4; ++m) {
        int r = wr + m * 16 + lr;
        a[m] = *(const short8*)((char*)&Al[cur][0] + r * 128 + (c2 ^ ((r & 7) << 4)));
      }
#pragma unroll
      for (int n = 0; n < 4; ++n) {
        int r = wc + n * 16 + lr;
        b[n] = *(const short8*)((char*)&Bl[cur][0] + r * 128 + (c2 ^ ((r & 7) << 4)));
      }
#pragma unroll
      for (int m = 0; m < 4; ++m)
#pragma unroll
        for (int n = 0; n < 4; ++n)
          acc[m][n] = __builtin_amdgcn_mfma_f32_16x16x32_bf16(a[m], b[n], acc[m][n], 0, 0, 0);
    }
    __syncthreads();
    cur ^= 1;
  }

  const int rbase = (l >> 4) * 4;
  if (Cf) {
#pragma unroll
    for (int m = 0; m < 4; ++m)
#pragma unroll
      for (int rg = 0; rg < 4; ++rg) {
        int row = row0 + wr + m * 16 + rbase + rg;
#pragma unroll
        for (int n = 0; n < 4; ++n) {
          int col = col0 + wc + n * 16 + lr;
          Cf[(size_t)row * N + col] = acc[m][n][rg] + bias[col];
        }
      }
  } else {
    unsigned short* Cp = Cb + (size_t)blockIdx.z * (size_t)(gridDim.y * 128) * N;
#pragma unroll
    for (int m = 0; m < 4; ++m)
#pragma unroll
      for (int rg = 0; rg < 4; ++rg) {
        int row = row0 + wr + m * 16 + rbase + rg;
#pragma unroll
        for (int n = 0; n < 4; ++n) {
          int col = col0 + wc + n * 16 + lr;
          Cp[(size_t)row * N + col] = bf16u(acc[m][n][rg]);
        }
      }
  }
}

// ---------- LSTM elementwise: z = z_lat(f32) + p0(bf16) + p1(bf16) ----------
__global__ __launch_bounds__(256) void k_lstm(const float* __restrict__ z_lat,
                                              const unsigned short* __restrict__ zp,
                                              float* __restrict__ c_st,
                                              unsigned short* __restrict__ A1,
                                              unsigned short* __restrict__ A2,
                                              const float* __restrict__ Wmu,
                                              const float* __restrict__ bmu,
                                              float* __restrict__ out, int t) {
  __shared__ float red[4];
  const size_t Z1 = (size_t)1024 * 4096;
  int r = blockIdx.x; int tid = threadIdx.x; int j = tid * 4;
  float g4[4][4];
#pragma unroll
  for (int g = 0; g < 4; ++g) {
    const float4 zl = *(const float4*)&z_lat[(size_t)r * 4096 + g * 1024 + j];
    const ushort4 p0 = *(const ushort4*)&zp[(size_t)r * 4096 + g * 1024 + j];
    const ushort4 p1 = *(const ushort4*)&zp[Z1 + (size_t)r * 4096 + g * 1024 + j];
    g4[g][0] = zl.x + b2f(p0.x) + b2f(p1.x);
    g4[g][1] = zl.y + b2f(p0.y) + b2f(p1.y);
    g4[g][2] = zl.z + b2f(p0.z) + b2f(p1.z);
    g4[g][3] = zl.w + b2f(p0.w) + b2f(p1.w);
  }
  const float4 cv = *(const float4*)&c_st[(size_t)r * 1024 + j];
  const float4 wm = *(const float4*)&Wmu[j];
  float cc[4] = {cv.x, cv.y, cv.z, cv.w}, wv[4] = {wm.x, wm.y, wm.z, wm.w};
  float cn[4], hn[4];
  float part = 0.f;
#pragma unroll
  for (int q = 0; q < 4; ++q) {
    float c2 = sigmoidf_(g4[1][q]) * cc[q] + sigmoidf_(g4[0][q]) * tanhf_(g4[2][q]);
    float h2 = sigmoidf_(g4[3][q]) * tanhf_(c2);
    cn[q] = c2; hn[q] = h2; part += h2 * wv[q];
  }
  *(float4*)&c_st[(size_t)r * 1024 + j] = make_float4(cn[0], cn[1], cn[2], cn[3]);
  *(ushort4*)&A2[(size_t)r * 2048 + j]        = pack4(hn[0], hn[1], hn[2], hn[3]);
  *(ushort4*)&A2[(size_t)r * 2048 + 1024 + j] = pack4(cn[0], cn[1], cn[2], cn[3]);
  *(ushort4*)&A1[(size_t)r * 2048 + 1024 + j] = pack4(hn[0], hn[1], hn[2], hn[3]);
#pragma unroll
  for (int off = 32; off > 0; off >>= 1) part += __shfl_down(part, off, 64);
  if ((tid & 63) == 0) red[tid >> 6] = part;
  __syncthreads();
  if (tid == 0) out[(size_t)r * T_ + t] = red[0] + red[1] + red[2] + red[3] + bmu[0];
}

// ---------- attention: spre = s_lat(f32) + sum8 partial(bf16) -> tanh -> softmax -> ctx ----------
__global__ __launch_bounds__(256) void k_attn(const float* __restrict__ s_lat,
                                              const unsigned short* __restrict__ sp8,
                                              const float* __restrict__ latent,
                                              unsigned short* __restrict__ A1) {
  __shared__ float red[4];
  const size_t P = (size_t)1024 * 1024;
  int r = blockIdx.x; int tid = threadIdx.x; int j = tid * 4;
  const float4 sl = *(const float4*)&s_lat[(size_t)r * 1024 + j];
  float sv[4] = {sl.x, sl.y, sl.z, sl.w};
#pragma unroll
  for (int sidx = 0; sidx < 8; ++sidx) {
    const ushort4 q = *(const ushort4*)&sp8[sidx * P + (size_t)r * 1024 + j];
    sv[0] += b2f(q.x); sv[1] += b2f(q.y); sv[2] += b2f(q.z); sv[3] += b2f(q.w);
  }
  float s[4] = {tanhf_(sv[0]), tanhf_(sv[1]), tanhf_(sv[2]), tanhf_(sv[3])};
  float mx = fmaxf(fmaxf(s[0], s[1]), fmaxf(s[2], s[3]));
#pragma unroll
  for (int off = 32; off > 0; off >>= 1) mx = fmaxf(mx, __shfl_xor(mx, off, 64));
  if ((tid & 63) == 0) red[tid >> 6] = mx;
  __syncthreads();
  mx = fmaxf(fmaxf(red[0], red[1]), fmaxf(red[2], red[3]));
  __syncthreads();
  float e[4], ps = 0.f;
#pragma unroll
  for (int q = 0; q < 4; ++q) { e[q] = __expf(s[q] - mx); ps += e[q]; }
#pragma unroll
  for (int off = 32; off > 0; off >>= 1) ps += __shfl_xor(ps, off, 64);
  if ((tid & 63) == 0) red[tid >> 6] = ps;
  __syncthreads();
  float inv = 1.f / (red[0] + red[1] + red[2] + red[3]);
  const float4 lv = *(const float4*)&latent[(size_t)r * 1024 + j];
  float lvv[4] = {lv.x, lv.y, lv.z, lv.w};
  *(ushort4*)&A1[(size_t)r * 2048 + j] =
      pack4(e[0] * inv * lvv[0], e[1] * inv * lvv[1], e[2] * inv * lvv[2], e[3] * inv * lvv[3]);
}

extern "C" void kernel_launch(void* const* d_in, const int* in_sizes, int n_in,
                              void* d_out, int out_size, void* d_ws, size_t ws_size,
                              hipStream_t stream) {
  const float* latent = (const float*)d_in[0];
  const float* h0  = (const float*)d_in[1];
  const float* c0  = (const float*)d_in[2];
  const float* Wk  = (const float*)d_in[3];
  const float* Wr  = (const float*)d_in[4];
  const float* b   = (const float*)d_in[5];
  const float* W1  = (const float*)d_in[6];
  const float* b1  = (const float*)d_in[7];
  const float* W2  = (const float*)d_in[8];
  const float* b2  = (const float*)d_in[9];
  const float* Wmu = (const float*)d_in[10];
  const float* bmu = (const float*)d_in[11];
  float* out = (float*)d_out;

  char* p = (char*)d_ws;
  auto alloc = [&](size_t bytes) { void* r = (void*)p; p += (bytes + 255) & ~(size_t)255; return r; };
  unsigned short* Wzh_t = (unsigned short*)alloc((size_t)4096 * 2048 * 2);
  unsigned short* Wk1_t = (unsigned short*)alloc((size_t)4096 * 1024 * 2);
  unsigned short* W1t   = (unsigned short*)alloc((size_t)1024 * 1024 * 2);
  unsigned short* W2t   = (unsigned short*)alloc((size_t)1024 * 2048 * 2);
  unsigned short* latbf = (unsigned short*)alloc((size_t)1024 * 1024 * 2);
  unsigned short* A1    = (unsigned short*)alloc((size_t)1024 * 2048 * 2);  // [ctx | h] bf16
  unsigned short* A2    = (unsigned short*)alloc((size_t)1024 * 2048 * 2);  // [h | c] bf16
  float* z_lat  = (float*)alloc((size_t)1024 * 4096 * 4);
  float* s_lat  = (float*)alloc((size_t)1024 * 1024 * 4);
  unsigned short* z_part = (unsigned short*)alloc((size_t)2 * 1024 * 4096 * 2);
  unsigned short* spre_p = (unsigned short*)alloc((size_t)8 * 1024 * 1024 * 2);
  float* c_st   = (float*)alloc((size_t)1024 * 1024 * 4);
  float* bias_s = (float*)alloc((size_t)1024 * 4);

  dim3 tb(32, 8);
  k_transpose<<<dim3(128, 32), tb, 0, stream>>>(Wk, 4096, Wk1_t, 1024, 0);
  k_transpose<<<dim3(128, 32), tb, 0, stream>>>(Wk + (size_t)1024 * 4096, 4096, Wzh_t, 2048, 0);
  k_transpose<<<dim3(128, 32), tb, 0, stream>>>(Wr, 4096, Wzh_t, 2048, 1024);
  k_transpose<<<dim3(32, 64), tb, 0, stream>>>(W2, 1024, W2t, 2048, 0);
  k_transpose<<<dim3(32, 32), tb, 0, stream>>>(W1, 1024, W1t, 1024, 0);

  k_init<<<1024, 256, 0, stream>>>(h0, c0, latent, A1, A2, latbf, c_st);
  k_bias<<<4, 256, 0, stream>>>(b1, b2, bias_s);

  // setup GEMMs (f32 + bias): z_lat = latent@Wk_top + b ; s_lat = latent@W1 + (b1+b2)
  k_gemm<<<dim3(32, 8, 1), 256, 0, stream>>>(latbf, 1024, Wk1_t, 1024, 1024, b, z_lat, nullptr, 4096);
  k_gemm<<<dim3(8, 8, 1), 256, 0, stream>>>(latbf, 1024, W1t, 1024, 1024, bias_s, s_lat, nullptr, 1024);

  // initial attention from (h0, c0)
  k_gemm<<<dim3(8, 8, 8), 256, 0, stream>>>(A2, 2048, W2t, 2048, 256, nullptr, nullptr, spre_p, 1024);
  k_attn<<<1024, 256, 0, stream>>>(s_lat, spre_p, latent, A1);

  for (int t = 0; t < T_; ++t) {
    k_gemm<<<dim3(32, 8, 2), 256, 0, stream>>>(A1, 2048, Wzh_t, 2048, 1024, nullptr, nullptr, z_part, 4096);
    k_lstm<<<1024, 256, 0, stream>>>(z_lat, z_part, c_st, A1, A2, Wmu, bmu, out, t);
    if (t < T_ - 1) {
      k_gemm<<<dim3(8, 8, 8), 256, 0, stream>>>(A2, 2048, W2t, 2048, 256, nullptr, nullptr, spre_p, 1024);
      k_attn<<<1024, 256, 0, stream>>>(s_lat, spre_p, latent, A1);
    }
  }
}